// Round 9
// baseline (1137.971 us; speedup 1.0000x reference)
//
#include <hip/hip_runtime.h>
#include <hip/hip_fp16.h>
#include <stdint.h>

#define NN 100000
#define NE 1600000
#define NPART 8
// chunked activation layout: [8][NN][16] fp16 (col c lives at chunk c>>4, word c&15)

typedef _Float16 f16x8 __attribute__((ext_vector_type(8)));
typedef float f32x4 __attribute__((ext_vector_type(4)));

// ---------------- CSR build ----------------
__global__ void hist_kernel(const int* __restrict__ ei, int* __restrict__ hist) {
    int t = blockIdx.x * blockDim.x + threadIdx.x;
    int e4 = t * 4;
    if (e4 >= NE) return;
    int* hp = hist + (size_t)(blockIdx.x & (NPART - 1)) * NN;
    int4 d = *(const int4*)(ei + NE + e4);
    atomicAdd(&hp[d.x], 1);
    atomicAdd(&hp[d.y], 1);
    atomicAdd(&hp[d.z], 1);
    atomicAdd(&hp[d.w], 1);
}

__global__ void scan_partial(const int* __restrict__ hist, int* __restrict__ excl,
                             int* __restrict__ bsums) {
    __shared__ int ts[256];
    int t = threadIdx.x;
    int base = blockIdx.x * 1024 + t * 4;
    int v0 = 0, v1 = 0, v2 = 0, v3 = 0;
    if (base < NN) {  // NN%4==0
#pragma unroll
        for (int p = 0; p < NPART; ++p) {
            int4 v = *(const int4*)(hist + (size_t)p * NN + base);
            v0 += v.x; v1 += v.y; v2 += v.z; v3 += v.w;
        }
    }
    int s3 = v0 + v1 + v2 + v3;
    ts[t] = s3;
    __syncthreads();
    int sum = s3;
    for (int off = 1; off < 256; off <<= 1) {
        int x = (t >= off) ? ts[t - off] : 0;
        __syncthreads();
        sum += x;
        ts[t] = sum;
        __syncthreads();
    }
    if (t == 255) bsums[blockIdx.x] = sum;
    int pre = sum - s3;
    if (base < NN) {
        *(int4*)(excl + base) = make_int4(pre, pre + v0, pre + v0 + v1, pre + v0 + v1 + v2);
    }
}

__global__ void scan_sums(int* __restrict__ bsums, int nb) {
    __shared__ int ts[128];
    int t = threadIdx.x;
    int v = (t < nb) ? bsums[t] : 0;
    ts[t] = v;
    __syncthreads();
    int sum = v;
    for (int off = 1; off < 128; off <<= 1) {
        int x = (t >= off) ? ts[t - off] : 0;
        __syncthreads();
        sum += x;
        ts[t] = sum;
        __syncthreads();
    }
    if (t < nb) bsums[t] = sum - v;
}

__global__ void scan_finalize(const int* __restrict__ excl, const int* __restrict__ bsums,
                              const int* __restrict__ hist,
                              int* __restrict__ rowptr, int* __restrict__ cursors) {
    int i = blockIdx.x * blockDim.x + threadIdx.x;
    if (i < NN) {
        int run = excl[i] + bsums[i >> 10];
        rowptr[i] = run;
#pragma unroll
        for (int p = 0; p < NPART; ++p) {
            cursors[(size_t)p * NN + i] = run;
            run += hist[(size_t)p * NN + i];
        }
    } else if (i == NN) {
        rowptr[NN] = NE;
    }
}

// single-pass fill (round-7 known-good: ~127us)
__global__ void fill_kernel(const int* __restrict__ ei, int* __restrict__ cursors,
                            int* __restrict__ esrc) {
    int t = blockIdx.x * blockDim.x + threadIdx.x;
    int e4 = t * 4;
    if (e4 >= NE) return;
    int* cp = cursors + (size_t)(blockIdx.x & (NPART - 1)) * NN;
    int4 s = *(const int4*)(ei + e4);
    int4 d = *(const int4*)(ei + NE + e4);
    int pos;
    pos = atomicAdd(&cp[d.x], 1); esrc[pos] = s.x;
    pos = atomicAdd(&cp[d.y], 1); esrc[pos] = s.y;
    pos = atomicAdd(&cp[d.z], 1); esrc[pos] = s.z;
    pos = atomicAdd(&cp[d.w], 1); esrc[pos] = s.w;
}

// ---------------- convert h (fp32 row-major) -> chunked fp16 ----------------
__global__ void cvt16_kernel(const float* __restrict__ in, __half* __restrict__ xc) {
    int t = blockIdx.x * blockDim.x + threadIdx.x;  // NN*16 threads
    if (t >= NN * 16) return;
    int n = t >> 4, i = t & 15;           // 8 cols starting at 8*i
    const float* ip = in + (size_t)n * 128 + 8 * i;
    float4 v0 = *(const float4*)ip;
    float4 v1 = *(const float4*)(ip + 4);
    uint4 o;
    __half2* oh = (__half2*)&o;
    oh[0] = __float22half2_rn(make_float2(v0.x, v0.y));
    oh[1] = __float22half2_rn(make_float2(v0.z, v0.w));
    oh[2] = __float22half2_rn(make_float2(v1.x, v1.y));
    oh[3] = __float22half2_rn(make_float2(v1.z, v1.w));
    *(uint4*)(xc + ((size_t)(i >> 1) * NN + n) * 16 + (i & 1) * 8) = o;
}

// ---------------- chunked SPMM: x'[c] = y[c] + agg(y[c]) + b[c] ----------------
// ONE CHUNK PER LAUNCH (host loops 8x) -> the 3.2MB Y-slice is the only L2
// working set. esrc reads and X writes are non-temporal (no L2 pollution).
#define SPMM_PB 3125  // NN*8/256
__global__ __launch_bounds__(256) void spmm128c_kernel(
    const __half* __restrict__ yc, const int* __restrict__ rowptr,
    const int* __restrict__ esrc, const float* __restrict__ bias,
    __half* __restrict__ xc, int chunk) {
    int g = blockIdx.x * 32 + (threadIdx.x >> 3);  // node; 3125*32 == NN exactly
    const int sub = threadIdx.x & 7;
    const int gbase = threadIdx.x & 56;
    const __half* ybase = yc + (size_t)chunk * NN * 16 + 2 * sub;
    int start = rowptr[g], end = rowptr[g + 1];
    float ax = 0.f, ay = 0.f;
    for (int j = start; j < end; j += 8) {
        int myidx = (j + sub < end) ? __builtin_nontemporal_load(esrc + j + sub) : 0;
        int cnt = min(8, end - j);
        int q = 0;
        for (; q + 4 <= cnt; q += 4) {
            int s0 = __shfl(myidx, gbase + q);
            int s1 = __shfl(myidx, gbase + q + 1);
            int s2 = __shfl(myidx, gbase + q + 2);
            int s3 = __shfl(myidx, gbase + q + 3);
            uint v0 = *(const uint*)(ybase + (size_t)s0 * 16);
            uint v1 = *(const uint*)(ybase + (size_t)s1 * 16);
            uint v2 = *(const uint*)(ybase + (size_t)s2 * 16);
            uint v3 = *(const uint*)(ybase + (size_t)s3 * 16);
            float2 f;
            f = __half22float2(*(__half2*)&v0); ax += f.x; ay += f.y;
            f = __half22float2(*(__half2*)&v1); ax += f.x; ay += f.y;
            f = __half22float2(*(__half2*)&v2); ax += f.x; ay += f.y;
            f = __half22float2(*(__half2*)&v3); ax += f.x; ay += f.y;
        }
        for (; q < cnt; ++q) {
            int s0 = __shfl(myidx, gbase + q);
            uint v0 = *(const uint*)(ybase + (size_t)s0 * 16);
            float2 f = __half22float2(*(__half2*)&v0);
            ax += f.x; ay += f.y;
        }
    }
    uint sv = *(const uint*)(ybase + (size_t)g * 16);
    float2 sf = __half22float2(*(__half2*)&sv);
    float2 bb = *(const float2*)(bias + 16 * chunk + 2 * sub);
    ax += sf.x + bb.x;
    ay += sf.y + bb.y;
    __half2 hv = __float22half2_rn(make_float2(ax, ay));
    __builtin_nontemporal_store(*(uint*)&hv,
        (uint*)(xc + (size_t)chunk * NN * 16 + (size_t)g * 16 + 2 * sub));
}

// ---------------- SPMM 40-wide final: out = z + agg(z) + b_out (fp32 out) ----------------
__global__ __launch_bounds__(256) void spmm40_kernel(
    const __half* __restrict__ z16, const int* __restrict__ rowptr,
    const int* __restrict__ esrc, const float* __restrict__ bout,
    float* __restrict__ out) {
    int grp = (blockIdx.x * blockDim.x + threadIdx.x) >> 4;
    if (grp >= NN) return;
    const int sub = threadIdx.x & 15;
    const int gbase = threadIdx.x & 48;
    const int hoff = sub * 4;
    int start = rowptr[grp], end = rowptr[grp + 1];
    float a[4];
#pragma unroll
    for (int k = 0; k < 4; ++k) a[k] = 0.f;
    for (int j = start; j < end; j += 16) {
        int myidx = (j + sub < end) ? __builtin_nontemporal_load(esrc + j + sub) : 0;
        int cnt = min(16, end - j);
        int q = 0;
        for (; q + 4 <= cnt; q += 4) {
            int s0 = __shfl(myidx, gbase + q);
            int s1 = __shfl(myidx, gbase + q + 1);
            int s2 = __shfl(myidx, gbase + q + 2);
            int s3 = __shfl(myidx, gbase + q + 3);
            uint2 v0 = *(const uint2*)(z16 + (size_t)s0 * 40 + hoff);
            uint2 v1 = *(const uint2*)(z16 + (size_t)s1 * 40 + hoff);
            uint2 v2 = *(const uint2*)(z16 + (size_t)s2 * 40 + hoff);
            uint2 v3 = *(const uint2*)(z16 + (size_t)s3 * 40 + hoff);
            const __half2* h;
            h = (const __half2*)&v0;
            { float2 f = __half22float2(h[0]); a[0]+=f.x; a[1]+=f.y; f = __half22float2(h[1]); a[2]+=f.x; a[3]+=f.y; }
            h = (const __half2*)&v1;
            { float2 f = __half22float2(h[0]); a[0]+=f.x; a[1]+=f.y; f = __half22float2(h[1]); a[2]+=f.x; a[3]+=f.y; }
            h = (const __half2*)&v2;
            { float2 f = __half22float2(h[0]); a[0]+=f.x; a[1]+=f.y; f = __half22float2(h[1]); a[2]+=f.x; a[3]+=f.y; }
            h = (const __half2*)&v3;
            { float2 f = __half22float2(h[0]); a[0]+=f.x; a[1]+=f.y; f = __half22float2(h[1]); a[2]+=f.x; a[3]+=f.y; }
        }
        for (; q < cnt; ++q) {
            int s0 = __shfl(myidx, gbase + q);
            uint2 v0 = *(const uint2*)(z16 + (size_t)s0 * 40 + hoff);
            const __half2* h = (const __half2*)&v0;
            float2 f = __half22float2(h[0]); a[0]+=f.x; a[1]+=f.y;
            f = __half22float2(h[1]); a[2]+=f.x; a[3]+=f.y;
        }
    }
    if (sub < 10) {
        uint2 sv = *(const uint2*)(z16 + (size_t)grp * 40 + hoff);
        const __half2* h = (const __half2*)&sv;
        float2 f0 = __half22float2(h[0]);
        float2 f1 = __half22float2(h[1]);
        float4 bb = *(const float4*)(bout + hoff);
        float4 o;
        o.x = f0.x + bb.x + a[0];
        o.y = f0.y + bb.y + a[1];
        o.z = f1.x + bb.z + a[2];
        o.w = f1.y + bb.w + a[3];
        *(float4*)(out + (size_t)grp * 40 + hoff) = o;
    }
}

// ---------------- MFMA GEMM: Yc = fp16( Xc @ W ), chunked in/out ----------------
#define G128_WAVES 3128
__global__ __launch_bounds__(256) void gemm128_mfma_kernel(
    const __half* __restrict__ A16c, const float* __restrict__ W,
    __half* __restrict__ Y16c) {
    const int wid = (blockIdx.x * 256 + threadIdx.x) >> 6;
    const int lane = threadIdx.x & 63;
    const int bl = lane & 15;
    const int bg = lane >> 4;

    f16x8 bf[8][4];
#pragma unroll
    for (int n = 0; n < 8; ++n) {
#pragma unroll
        for (int kk = 0; kk < 4; ++kk) {
            f16x8 t;
#pragma unroll
            for (int i = 0; i < 8; ++i) {
                float w = W[(size_t)(32 * kk + 8 * bg + i) * 128 + 16 * n + bl];
                t[i] = (_Float16)w;
            }
            bf[n][kk] = t;
        }
    }

    for (int tile = wid; tile < NN / 16; tile += G128_WAVES) {
        const int row0 = tile * 16;
        f16x8 af[4];
#pragma unroll
        for (int kk = 0; kk < 4; ++kk) {
            af[kk] = *(const f16x8*)(A16c +
                ((size_t)((bg >> 1) + 2 * kk) * NN + row0 + bl) * 16 + (bg & 1) * 8);
        }
        f32x4 acc[8];
#pragma unroll
        for (int n = 0; n < 8; ++n) acc[n] = (f32x4){0.f, 0.f, 0.f, 0.f};
#pragma unroll
        for (int kk = 0; kk < 4; ++kk) {
#pragma unroll
            for (int n = 0; n < 8; ++n)
                acc[n] = __builtin_amdgcn_mfma_f32_16x16x32_f16(af[kk], bf[n][kk], acc[n], 0, 0, 0);
        }
#pragma unroll
        for (int n = 0; n < 8; ++n) {
#pragma unroll
            for (int r = 0; r < 4; ++r)
                Y16c[((size_t)n * NN + row0 + 4 * bg + r) * 16 + bl] = __float2half(acc[n][r]);
        }
    }
}

// ---------------- GEMM: Z16[M][40] = fp16( chunked A @ W[128][40] ) ----------------
__global__ __launch_bounds__(256) void gemm40_kernel(
    const __half* __restrict__ A16c, const float* __restrict__ W,
    __half* __restrict__ Z16, int M) {
    __shared__ float As[64][132];
    __shared__ float Wls[128 * 40];
    const int t = threadIdx.x;
    const int br = blockIdx.x * 64;
#pragma unroll
    for (int i = 0; i < 5; ++i) {
        int idx = t + 256 * i;
        *(float4*)&Wls[idx * 4] = *(const float4*)(W + idx * 4);
    }
    {
        int r = t >> 2;
        int row = min(br + r, M - 1);
#pragma unroll
        for (int i = 0; i < 4; ++i) {
            int cc = (t & 3) + 4 * i;  // 8-half chunk idx 0..15; col0 = 8*cc
            uint4 v = *(const uint4*)(A16c +
                ((size_t)(cc >> 1) * NN + row) * 16 + (cc & 1) * 8);
            const __half2* h = (const __half2*)&v;
#pragma unroll
            for (int k = 0; k < 4; ++k) {
                float2 f = __half22float2(h[k]);
                As[r][8 * cc + 2 * k] = f.x;
                As[r][8 * cc + 2 * k + 1] = f.y;
            }
        }
    }
    __syncthreads();
    const int r = t >> 2;
    const int tn10 = (t & 3) * 10;
    float acc[10];
#pragma unroll
    for (int j = 0; j < 10; ++j) acc[j] = 0.f;
#pragma unroll 4
    for (int kk = 0; kk < 128; ++kk) {
        float a0 = As[r][kk];
        const float* wp = &Wls[kk * 40 + tn10];
#pragma unroll
        for (int j = 0; j < 10; ++j) acc[j] += a0 * wp[j];
    }
    int row = br + r;
    if (row < M) {
        __half* zp = Z16 + (size_t)row * 40 + tn10;
#pragma unroll
        for (int j = 0; j < 5; ++j) {
            __half2 hv = __float22half2_rn(make_float2(acc[2 * j], acc[2 * j + 1]));
            *(uint*)( (char*)zp + 4 * j ) = *(uint*)&hv;
        }
    }
}

extern "C" void kernel_launch(void* const* d_in, const int* in_sizes, int n_in,
                              void* d_out, int out_size, void* d_ws, size_t ws_size,
                              hipStream_t stream) {
    const float* h      = (const float*)d_in[0];
    const float* Ws     = (const float*)d_in[1];
    const float* bs     = (const float*)d_in[2];
    const float* W_out  = (const float*)d_in[3];
    const float* b_out  = (const float*)d_in[4];
    const int*   ei     = (const int*)d_in[5];
    float* out = (float*)d_out;

    char* p = (char*)d_ws;
    auto alloc = [&](size_t bytes) {
        char* r = p;
        p += (bytes + 255) & ~size_t(255);
        return r;
    };
    int* hist    = (int*)alloc((size_t)NPART * NN * 4);
    int* cursors = (int*)alloc((size_t)NPART * NN * 4);
    int* rowptr  = (int*)alloc((size_t)(NN + 1) * 4);
    int* bsums   = (int*)alloc(128 * 4);
    int* esrc    = (int*)alloc((size_t)NE * 4);
    __half* X16  = (__half*)alloc((size_t)NN * 128 * 2);       // chunked [8][NN][16]
    __half* Y16  = (__half*)alloc((size_t)NN * 128 * 2 + 256); // chunked / Z16 row-major

    // ---- CSR build ----
    hipMemsetAsync(hist, 0, (size_t)NPART * NN * 4, stream);
    const int eblocks = (NE / 4 + 255) / 256;  // 1563
    hist_kernel<<<eblocks, 256, 0, stream>>>(ei, hist);
    int nb = (NN + 1023) / 1024;
    scan_partial<<<nb, 256, 0, stream>>>(hist, esrc /*scratch*/, bsums);
    scan_sums<<<1, 128, 0, stream>>>(bsums, nb);
    scan_finalize<<<(NN + 256) / 256, 256, 0, stream>>>(esrc, bsums, hist, rowptr, cursors);
    fill_kernel<<<eblocks, 256, 0, stream>>>(ei, cursors, esrc);

    // ---- h -> chunked fp16 ----
    cvt16_kernel<<<(NN * 16 + 255) / 256, 256, 0, stream>>>(h, X16);

    // ---- layers 0..3: y = x@W (MFMA, chunked); x' = y + agg(y) + b (chunk-serial) ----
    for (int l = 0; l < 4; ++l) {
        gemm128_mfma_kernel<<<G128_WAVES / 4, 256, 0, stream>>>(
            X16, Ws + (size_t)l * 128 * 128, Y16);
        for (int c = 0; c < 8; ++c) {
            spmm128c_kernel<<<SPMM_PB, 256, 0, stream>>>(
                Y16, rowptr, esrc, bs + (size_t)l * 128, X16, c);
        }
    }
    // ---- layer 4: z = x4@W_out (row-major 40); out = z + agg(z) + b_out ----
    gemm40_kernel<<<(NN + 63) / 64, 256, 0, stream>>>(X16, W_out, Y16 /*as Z16*/, NN);
    spmm40_kernel<<<(NN * 16 + 255) / 256, 256, 0, stream>>>(Y16, rowptr, esrc, b_out, out);
}

// Round 10
// 548.960 us; speedup vs baseline: 2.0730x; 2.0730x over previous
//
#include <hip/hip_runtime.h>
#include <hip/hip_fp16.h>
#include <stdint.h>

#define NN 100000
#define NE 1600000
#define NB 196      // ceil(NN/512) buckets
#define DPB 512     // dsts per bucket
#define BCAP 12288  // bucket capacity (mean 8192, sd~90 -> 45 sigma headroom)

typedef _Float16 f16x8 __attribute__((ext_vector_type(8)));
typedef float f32x4 __attribute__((ext_vector_type(4)));

__device__ __forceinline__ void h8acc(float* a, uint4 v) {
    const __half2* h = (const __half2*)&v;
#pragma unroll
    for (int k = 0; k < 4; ++k) {
        float2 f = __half22float2(h[k]);
        a[2 * k] += f.x;
        a[2 * k + 1] += f.y;
    }
}

// ---------------- CSR build: bucket two-pass ----------------
// Pass A: bucket edges by dst>>9. Block: LDS count -> bulk reserve -> append.
__global__ __launch_bounds__(256) void bucketA_kernel(const int* __restrict__ ei,
                                                      int* __restrict__ gcur,
                                                      int* __restrict__ bdata) {
    __shared__ int sCnt[NB];
    __shared__ int sBase[NB];
    const int t = threadIdx.x;
    for (int i = t; i < NB; i += 256) sCnt[i] = 0;
    __syncthreads();
    const int base = blockIdx.x * 4096 + t * 16;
    int pk[16], bk[16];
    const bool act = base < NE;  // NE%16==0 -> all-or-nothing per thread
    if (act) {
#pragma unroll
        for (int i = 0; i < 4; ++i) {
            int4 s = *(const int4*)(ei + base + 4 * i);
            int4 d = *(const int4*)(ei + NE + base + 4 * i);
            bk[4*i+0] = d.x >> 9; pk[4*i+0] = s.x | ((d.x & 511) << 17);
            bk[4*i+1] = d.y >> 9; pk[4*i+1] = s.y | ((d.y & 511) << 17);
            bk[4*i+2] = d.z >> 9; pk[4*i+2] = s.z | ((d.z & 511) << 17);
            bk[4*i+3] = d.w >> 9; pk[4*i+3] = s.w | ((d.w & 511) << 17);
        }
#pragma unroll
        for (int i = 0; i < 16; ++i) atomicAdd(&sCnt[bk[i]], 1);
    }
    __syncthreads();
    for (int i = t; i < NB; i += 256) {
        int c = sCnt[i];
        sBase[i] = c ? atomicAdd(&gcur[i], c) : 0;
        sCnt[i] = 0;  // reuse as intra-block cursor
    }
    __syncthreads();
    if (act) {
#pragma unroll
        for (int i = 0; i < 16; ++i) {
            int b = bk[i];
            int r = atomicAdd(&sCnt[b], 1);
            bdata[(size_t)b * BCAP + sBase[b] + r] = pk[i];
        }
    }
}

// bucket prefix (1 block); also writes rowptr[NN]=NE
__global__ void bucket_scan_kernel(const int* __restrict__ gcur, int* __restrict__ bstart,
                                   int* __restrict__ rowptr_end) {
    __shared__ int ts[256];
    int t = threadIdx.x;
    int v = (t < NB) ? gcur[t] : 0;
    ts[t] = v;
    __syncthreads();
    int sum = v;
    for (int off = 1; off < 256; off <<= 1) {
        int x = (t >= off) ? ts[t - off] : 0;
        __syncthreads();
        sum += x;
        ts[t] = sum;
        __syncthreads();
    }
    if (t < NB) bstart[t] = sum - v;
    if (t == 0) rowptr_end[0] = NE;
}

// Pass B: one workgroup per bucket. Stage to LDS, per-dst count+scan -> rowptr
// slice + in-LDS cursors -> scatter esrc into this bucket's exclusive window.
__global__ __launch_bounds__(256) void bucketB_kernel(
    const int* __restrict__ gcur, const int* __restrict__ bstart,
    const int* __restrict__ bdata, int* __restrict__ rowptr, int* __restrict__ esrc) {
    __shared__ int sE[BCAP];   // 48KB
    __shared__ int sC[DPB];    // counts -> cursors
    __shared__ int sX[DPB];    // exclusive prefix
    __shared__ int ts[256];
    const int b = blockIdx.x, t = threadIdx.x;
    const int cnt = gcur[b];
    const int bs = bstart[b];
    for (int i = t; i < cnt; i += 256) sE[i] = bdata[(size_t)b * BCAP + i];
    for (int i = t; i < DPB; i += 256) sC[i] = 0;
    __syncthreads();
    for (int i = t; i < cnt; i += 256) atomicAdd(&sC[sE[i] >> 17], 1);
    __syncthreads();
    int c0 = sC[2 * t], c1 = sC[2 * t + 1];
    int ps = c0 + c1;
    ts[t] = ps;
    __syncthreads();
    int sum = ps;
    for (int off = 1; off < 256; off <<= 1) {
        int x = (t >= off) ? ts[t - off] : 0;
        __syncthreads();
        sum += x;
        ts[t] = sum;
        __syncthreads();
    }
    sX[2 * t] = sum - ps;
    sX[2 * t + 1] = sum - ps + c0;
    __syncthreads();
    const int dst0 = b * DPB;
    for (int i = t; i < DPB; i += 256) {
        int v = bs + sX[i];
        if (dst0 + i < NN) rowptr[dst0 + i] = v;
        sC[i] = v;  // cursor
    }
    __syncthreads();
    for (int i = t; i < cnt; i += 256) {
        int e = sE[i];
        int pos = atomicAdd(&sC[e >> 17], 1);
        esrc[pos] = e & 0x1FFFF;
    }
}

// ---------------- convert h (fp32) -> fp16 row-major ----------------
__global__ void cvt16_kernel(const float* __restrict__ in, __half* __restrict__ out16) {
    size_t i = (size_t)(blockIdx.x * blockDim.x + threadIdx.x) * 8;
    if (i >= (size_t)NN * 128) return;
    float4 v0 = *(const float4*)(in + i);
    float4 v1 = *(const float4*)(in + i + 4);
    uint4 o;
    __half2* oh = (__half2*)&o;
    oh[0] = __float22half2_rn(make_float2(v0.x, v0.y));
    oh[1] = __float22half2_rn(make_float2(v0.z, v0.w));
    oh[2] = __float22half2_rn(make_float2(v1.x, v1.y));
    oh[3] = __float22half2_rn(make_float2(v1.z, v1.w));
    *(uint4*)(out16 + i) = o;
}

// ---------------- SPMM: x' = y + agg(y) + b (fp16 rows) ----------------
__global__ __launch_bounds__(256) void spmm128_kernel(
    const __half* __restrict__ y16, const int* __restrict__ rowptr,
    const int* __restrict__ esrc, const float* __restrict__ bias,
    __half* __restrict__ x16) {
    int grp = (blockIdx.x * blockDim.x + threadIdx.x) >> 4;
    if (grp >= NN) return;
    const int sub = threadIdx.x & 15;
    const int gbase = threadIdx.x & 48;
    const int hoff = sub * 8;
    int start = rowptr[grp], end = rowptr[grp + 1];
    float a[8];
#pragma unroll
    for (int k = 0; k < 8; ++k) a[k] = 0.f;
    for (int j = start; j < end; j += 16) {
        int myidx = (j + sub < end) ? esrc[j + sub] : 0;
        int cnt = min(16, end - j);
        int q = 0;
        for (; q + 4 <= cnt; q += 4) {
            int s0 = __shfl(myidx, gbase + q);
            int s1 = __shfl(myidx, gbase + q + 1);
            int s2 = __shfl(myidx, gbase + q + 2);
            int s3 = __shfl(myidx, gbase + q + 3);
            uint4 v0 = *(const uint4*)(y16 + (size_t)s0 * 128 + hoff);
            uint4 v1 = *(const uint4*)(y16 + (size_t)s1 * 128 + hoff);
            uint4 v2 = *(const uint4*)(y16 + (size_t)s2 * 128 + hoff);
            uint4 v3 = *(const uint4*)(y16 + (size_t)s3 * 128 + hoff);
            h8acc(a, v0); h8acc(a, v1); h8acc(a, v2); h8acc(a, v3);
        }
        for (; q < cnt; ++q) {
            int s0 = __shfl(myidx, gbase + q);
            h8acc(a, *(const uint4*)(y16 + (size_t)s0 * 128 + hoff));
        }
    }
    h8acc(a, *(const uint4*)(y16 + (size_t)grp * 128 + hoff));
    float4 b0 = *(const float4*)(bias + hoff);
    float4 b1 = *(const float4*)(bias + hoff + 4);
    a[0] += b0.x; a[1] += b0.y; a[2] += b0.z; a[3] += b0.w;
    a[4] += b1.x; a[5] += b1.y; a[6] += b1.z; a[7] += b1.w;
    uint4 o;
    __half2* oh = (__half2*)&o;
#pragma unroll
    for (int k = 0; k < 4; ++k)
        oh[k] = __float22half2_rn(make_float2(a[2 * k], a[2 * k + 1]));
    *(uint4*)(x16 + (size_t)grp * 128 + hoff) = o;
}

// ---------------- SPMM 40-wide final: out = z + agg(z) + b_out (fp32 out) ----------------
__global__ __launch_bounds__(256) void spmm40_kernel(
    const __half* __restrict__ z16, const int* __restrict__ rowptr,
    const int* __restrict__ esrc, const float* __restrict__ bout,
    float* __restrict__ out) {
    int grp = (blockIdx.x * blockDim.x + threadIdx.x) >> 4;
    if (grp >= NN) return;
    const int sub = threadIdx.x & 15;
    const int gbase = threadIdx.x & 48;
    const int hoff = sub * 4;
    int start = rowptr[grp], end = rowptr[grp + 1];
    float a[4];
#pragma unroll
    for (int k = 0; k < 4; ++k) a[k] = 0.f;
    for (int j = start; j < end; j += 16) {
        int myidx = (j + sub < end) ? esrc[j + sub] : 0;
        int cnt = min(16, end - j);
        int q = 0;
        for (; q + 4 <= cnt; q += 4) {
            int s0 = __shfl(myidx, gbase + q);
            int s1 = __shfl(myidx, gbase + q + 1);
            int s2 = __shfl(myidx, gbase + q + 2);
            int s3 = __shfl(myidx, gbase + q + 3);
            uint2 v0 = *(const uint2*)(z16 + (size_t)s0 * 40 + hoff);
            uint2 v1 = *(const uint2*)(z16 + (size_t)s1 * 40 + hoff);
            uint2 v2 = *(const uint2*)(z16 + (size_t)s2 * 40 + hoff);
            uint2 v3 = *(const uint2*)(z16 + (size_t)s3 * 40 + hoff);
            const __half2* h;
            h = (const __half2*)&v0;
            { float2 f = __half22float2(h[0]); a[0]+=f.x; a[1]+=f.y; f = __half22float2(h[1]); a[2]+=f.x; a[3]+=f.y; }
            h = (const __half2*)&v1;
            { float2 f = __half22float2(h[0]); a[0]+=f.x; a[1]+=f.y; f = __half22float2(h[1]); a[2]+=f.x; a[3]+=f.y; }
            h = (const __half2*)&v2;
            { float2 f = __half22float2(h[0]); a[0]+=f.x; a[1]+=f.y; f = __half22float2(h[1]); a[2]+=f.x; a[3]+=f.y; }
            h = (const __half2*)&v3;
            { float2 f = __half22float2(h[0]); a[0]+=f.x; a[1]+=f.y; f = __half22float2(h[1]); a[2]+=f.x; a[3]+=f.y; }
        }
        for (; q < cnt; ++q) {
            int s0 = __shfl(myidx, gbase + q);
            uint2 v0 = *(const uint2*)(z16 + (size_t)s0 * 40 + hoff);
            const __half2* h = (const __half2*)&v0;
            float2 f = __half22float2(h[0]); a[0]+=f.x; a[1]+=f.y;
            f = __half22float2(h[1]); a[2]+=f.x; a[3]+=f.y;
        }
    }
    if (sub < 10) {
        uint2 sv = *(const uint2*)(z16 + (size_t)grp * 40 + hoff);
        const __half2* h = (const __half2*)&sv;
        float2 f0 = __half22float2(h[0]);
        float2 f1 = __half22float2(h[1]);
        float4 bb = *(const float4*)(bout + hoff);
        float4 o;
        o.x = f0.x + bb.x + a[0];
        o.y = f0.y + bb.y + a[1];
        o.z = f1.x + bb.z + a[2];
        o.w = f1.y + bb.w + a[3];
        *(float4*)(out + (size_t)grp * 40 + hoff) = o;
    }
}

// ---------------- MFMA GEMM: Y16[M][128] = fp16( A16[M][128] @ W[128][128] ) ----------------
#define G128_WAVES 3128
__global__ __launch_bounds__(256) void gemm128_mfma_kernel(
    const __half* __restrict__ A16, const float* __restrict__ W,
    __half* __restrict__ Y16) {
    const int wid = (blockIdx.x * 256 + threadIdx.x) >> 6;
    const int lane = threadIdx.x & 63;
    const int bl = lane & 15;
    const int bg = lane >> 4;

    f16x8 bf[8][4];
#pragma unroll
    for (int n = 0; n < 8; ++n) {
#pragma unroll
        for (int kk = 0; kk < 4; ++kk) {
            f16x8 t;
#pragma unroll
            for (int i = 0; i < 8; ++i) {
                float w = W[(size_t)(32 * kk + 8 * bg + i) * 128 + 16 * n + bl];
                t[i] = (_Float16)w;
            }
            bf[n][kk] = t;
        }
    }

    for (int tile = wid; tile < NN / 16; tile += G128_WAVES) {
        const int row0 = tile * 16;
        const __half* Ap = A16 + (size_t)(row0 + bl) * 128 + 8 * bg;
        f16x8 af[4];
#pragma unroll
        for (int kk = 0; kk < 4; ++kk)
            af[kk] = *(const f16x8*)(Ap + 32 * kk);

        f32x4 acc[8];
#pragma unroll
        for (int n = 0; n < 8; ++n) acc[n] = (f32x4){0.f, 0.f, 0.f, 0.f};
#pragma unroll
        for (int kk = 0; kk < 4; ++kk) {
#pragma unroll
            for (int n = 0; n < 8; ++n)
                acc[n] = __builtin_amdgcn_mfma_f32_16x16x32_f16(af[kk], bf[n][kk], acc[n], 0, 0, 0);
        }
        __half* Yp = Y16 + (size_t)(row0 + 4 * bg) * 128 + bl;
#pragma unroll
        for (int n = 0; n < 8; ++n) {
#pragma unroll
            for (int r = 0; r < 4; ++r)
                Yp[(size_t)r * 128 + 16 * n] = __float2half(acc[n][r]);
        }
    }
}

// ---------------- GEMM: Z16[M][40] = fp16( A16[M][128] @ W[128][40] ) ----------------
__global__ __launch_bounds__(256) void gemm40_kernel(
    const __half* __restrict__ A16, const float* __restrict__ W,
    __half* __restrict__ Z16, int M) {
    __shared__ float As[64][132];
    __shared__ float Wls[128 * 40];
    const int t = threadIdx.x;
    const int br = blockIdx.x * 64;
#pragma unroll
    for (int i = 0; i < 5; ++i) {
        int idx = t + 256 * i;
        *(float4*)&Wls[idx * 4] = *(const float4*)(W + idx * 4);
    }
    {
        int r = t >> 2;
        int row = min(br + r, M - 1);
        const __half* Ap = A16 + (size_t)row * 128;
#pragma unroll
        for (int i = 0; i < 4; ++i) {
            int c = (t & 3) + 4 * i;
            uint4 v = *(const uint4*)(Ap + 8 * c);
            const __half2* h = (const __half2*)&v;
#pragma unroll
            for (int k = 0; k < 4; ++k) {
                float2 f = __half22float2(h[k]);
                As[r][8 * c + 2 * k] = f.x;
                As[r][8 * c + 2 * k + 1] = f.y;
            }
        }
    }
    __syncthreads();
    const int r = t >> 2;
    const int tn10 = (t & 3) * 10;
    float acc[10];
#pragma unroll
    for (int j = 0; j < 10; ++j) acc[j] = 0.f;
#pragma unroll 4
    for (int kk = 0; kk < 128; ++kk) {
        float a0 = As[r][kk];
        const float* wp = &Wls[kk * 40 + tn10];
#pragma unroll
        for (int j = 0; j < 10; ++j) acc[j] += a0 * wp[j];
    }
    int row = br + r;
    if (row < M) {
        __half* zp = Z16 + (size_t)row * 40 + tn10;
#pragma unroll
        for (int j = 0; j < 5; ++j) {
            __half2 hv = __float22half2_rn(make_float2(acc[2 * j], acc[2 * j + 1]));
            *(uint*)( (char*)zp + 4 * j ) = *(uint*)&hv;
        }
    }
}

extern "C" void kernel_launch(void* const* d_in, const int* in_sizes, int n_in,
                              void* d_out, int out_size, void* d_ws, size_t ws_size,
                              hipStream_t stream) {
    const float* h      = (const float*)d_in[0];
    const float* Ws     = (const float*)d_in[1];
    const float* bs     = (const float*)d_in[2];
    const float* W_out  = (const float*)d_in[3];
    const float* b_out  = (const float*)d_in[4];
    const int*   ei     = (const int*)d_in[5];
    float* out = (float*)d_out;

    char* p = (char*)d_ws;
    auto alloc = [&](size_t bytes) {
        char* r = p;
        p += (bytes + 255) & ~size_t(255);
        return r;
    };
    int* gcur    = (int*)alloc((size_t)NB * 4);
    int* bstart  = (int*)alloc((size_t)NB * 4);
    int* bdata   = (int*)alloc((size_t)NB * BCAP * 4);      // 9.6 MB
    int* rowptr  = (int*)alloc((size_t)(NN + 1) * 4);
    int* esrc    = (int*)alloc((size_t)NE * 4);             // 6.4 MB
    __half* X16  = (__half*)alloc((size_t)NN * 128 * 2);    // 25.6 MB
    __half* Y16  = (__half*)alloc((size_t)NN * 128 * 2 + 256);

    // ---- CSR build (bucket two-pass) ----
    hipMemsetAsync(gcur, 0, (size_t)NB * 4, stream);
    bucketA_kernel<<<(NE + 4095) / 4096, 256, 0, stream>>>(ei, gcur, bdata);
    bucket_scan_kernel<<<1, 256, 0, stream>>>(gcur, bstart, rowptr + NN);
    bucketB_kernel<<<NB, 256, 0, stream>>>(gcur, bstart, bdata, rowptr, esrc);

    // ---- h -> fp16 ----
    cvt16_kernel<<<(NN * 128 / 8 + 255) / 256, 256, 0, stream>>>(h, X16);

    // ---- layers 0..3: y = x@W (MFMA, fp16); x' = y + agg(y) + b ----
    const int spmm_grid = (NN * 16 + 255) / 256;
    for (int l = 0; l < 4; ++l) {
        gemm128_mfma_kernel<<<G128_WAVES / 4, 256, 0, stream>>>(
            X16, Ws + (size_t)l * 128 * 128, Y16);
        spmm128_kernel<<<spmm_grid, 256, 0, stream>>>(
            Y16, rowptr, esrc, bs + (size_t)l * 128, X16);
    }
    // ---- layer 4: z = x4@W_out; out = z + agg(z) + b_out ----
    gemm40_kernel<<<(NN + 63) / 64, 256, 0, stream>>>(X16, W_out, Y16 /*as Z16*/, NN);
    spmm40_kernel<<<spmm_grid, 256, 0, stream>>>(Y16, rowptr, esrc, b_out, out);
}